// Round 14
// baseline (186.709 us; speedup 1.0000x reference)
//
#include <hip/hip_runtime.h>

// PLELayer round-14: occupancy play. r13 profile: VALU 50%, MFMA 26%,
// conflicts ~4us, occupancy 34% -> latency-bound, no pipe saturated.
// NT 256->512 (8 waves/block, units 2/wave instead of 4/wave), same
// EPB=64 and identical per-block instruction mix. Resident becomes
// min(5 LDS-blocks, 32/8) = 4 blocks/CU = 32 waves/CU (100%) vs ~11.
// launch_bounds(512,4) = same 128-VGPR cap as r13 (no spill risk).
// Phase-2 gate/mix active on waves 0..3 only (su>=4 must NOT zero l1in:
// 16+su*4 would overflow into the next element's row).

#define NT 512
#define EPB 64

typedef unsigned short u16;
typedef unsigned int u32;
typedef __fp16 hv2 __attribute__((ext_vector_type(2)));
typedef __fp16 half8 __attribute__((ext_vector_type(8)));
typedef __attribute__((ext_vector_type(4))) float floatx4;

__device__ __forceinline__ u32 pkh2(float a, float b){
  hv2 v = __builtin_amdgcn_cvt_pkrtz(a, b);
  u32 r; __builtin_memcpy(&r, &v, 4); return r;
}
__device__ __forceinline__ float h2f(u16 v){
  __fp16 h; __builtin_memcpy(&h, &v, 2); return (float)h;
}
__device__ __forceinline__ hv2 u2h(u32 w){ hv2 v; __builtin_memcpy(&v, &w, 4); return v; }
__device__ __forceinline__ u32 h2u(hv2 v){ u32 w; __builtin_memcpy(&w, &v, 4); return w; }
__device__ __forceinline__ float dot2(u32 a, u32 b, float c){
  return __builtin_amdgcn_fdot2(u2h(a), u2h(b), c, false);
}
__device__ __forceinline__ void unp8(uint4 gw, float g8[8]){
  g8[0]=h2f((u16)(gw.x&0xffffu)); g8[1]=h2f((u16)(gw.x>>16));
  g8[2]=h2f((u16)(gw.y&0xffffu)); g8[3]=h2f((u16)(gw.y>>16));
  g8[4]=h2f((u16)(gw.z&0xffffu)); g8[5]=h2f((u16)(gw.z>>16));
  g8[6]=h2f((u16)(gw.w&0xffffu)); g8[7]=h2f((u16)(gw.w>>16));
}

// ---- ws layout ----
#define W1F0 0          // [16u][3s][4t][64l][4]  = 49152 u32 (f16 pairs)
#define W2F0 49152      // [16u][2ks][64l][4]     =  8192 (h'(q,ks,j) perm)
#define W1F1 57344      // [15u][4t][64l][4]      = 15360
#define W2F1 72704      // [15u][2ks][64l][4]     =  7680 (h' perm)
#define OFF_b1P0 80384  // [16][64] natural
#define OFF_b2P0 81408  // [16][16] cols 8..15 zero
#define OFF_b1P1 81664  // [15][64] natural
#define OFF_b2P1 82624  // [15][16] cols 8..15 zero
#define OFF_G0W3 82864  // [3][8][6]
#define OFF_SG0W3 83008 // [8][12]
#define OFF_G1W3 83104  // [3][8][6]
#define OFF_TW   83248  // [3][8] fp32 (unused by kernel now, kept)
#define OFF_Tb   83272  // [3]
#define OFF_TWH  83275  // [3][4] u32: packed f16 pairs of tower_W
#define CVT_TOTAL 83287

struct PSrc { const float* p[33]; };

__global__ void cvt_kernel(PSrc S, u32* __restrict__ wsU, float* __restrict__ wsF){
  int i = blockIdx.x*256 + threadIdx.x;
  if (i >= CVT_TOTAL) return;
  if (i < 49152){  // W1F0: lane holds W1[k=s*32+q*8+j][h=t*16+c16], k>=72 -> 0
    int j2 = i & 3, l = (i>>2)&63, tt = (i>>8)&3;
    int rest = i >> 10; int s = rest % 3, u = rest / 3;
    int k0 = s*32 + (l>>4)*8 + 2*j2;
    int h  = tt*16 + (l&15);
    const float* src = (u<9)  ? S.p[0]  + (u*72)*64
                     : (u<12) ? S.p[4]  + ((u-9)*72)*64
                     : (u<15) ? S.p[8]  + ((u-12)*72)*64
                              : S.p[13];
    float lo = (k0   < 72) ? src[(k0  )*64 + h] : 0.f;
    float hi = (k0+1 < 72) ? src[(k0+1)*64 + h] : 0.f;
    wsU[i] = pkh2(lo, hi);
    return;
  }
  i -= 49152;
  if (i < 8192){   // W2F0: W2[h'(q,ks,j)][n=l&15], n>=8 -> 0
    int j2 = i & 3, l = (i>>2)&63, ks = (i>>8)&1, u = i>>9;
    int q = l >> 4, n = l & 15;
    int h0 = (2*ks + ((2*j2)>>2))*16 + q*4 + ((2*j2)&3);
    const float* src = (u<9)  ? S.p[2]  + u*512
                     : (u<12) ? S.p[6]  + (u-9)*512
                     : (u<15) ? S.p[10] + (u-12)*512
                              : S.p[15];
    float lo = (n<8) ? src[h0*8 + n] : 0.f;
    float hi = (n<8) ? src[(h0+1)*8 + n] : 0.f;
    wsU[W2F0 + i] = pkh2(lo, hi);
    return;
  }
  i -= 8192;
  if (i < 15360){  // W1F1: lane holds W1[k=q*8+j][h=t*16+c16], k>=8 -> 0
    int j2 = i & 3, l = (i>>2)&63, tt = (i>>8)&3, u = i>>10;
    int k0 = (l>>4)*8 + 2*j2;
    int n = tt*16 + (l&15);
    const float* src = (u<9) ? S.p[18] + (u*8)*64
                     : (u<12) ? S.p[22] + ((u-9)*8)*64
                              : S.p[26] + ((u-12)*8)*64;
    float lo = (k0   < 8) ? src[(k0  )*64 + n] : 0.f;
    float hi = (k0+1 < 8) ? src[(k0+1)*64 + n] : 0.f;
    wsU[W1F1 + i] = pkh2(lo, hi);
    return;
  }
  i -= 15360;
  if (i < 7680){   // W2F1: h'(q,ks,j) permutation, n>=8 -> 0
    int j2 = i & 3, l = (i>>2)&63, ks = (i>>8)&1, u = i>>9;
    int q = l >> 4, n = l & 15;
    int h0 = (2*ks + ((2*j2)>>2))*16 + q*4 + ((2*j2)&3);
    const float* src = (u<9) ? S.p[20] + u*512
                     : (u<12) ? S.p[24] + (u-9)*512
                              : S.p[28] + (u-12)*512;
    float lo = (n<8) ? src[h0*8 + n] : 0.f;
    float hi = (n<8) ? src[(h0+1)*8 + n] : 0.f;
    wsU[W2F1 + i] = pkh2(lo, hi);
    return;
  }
  i -= 7680;
  if (i < 1024){   // b1P0 natural [u][64]
    int u = i>>6;
    const float* src = (u<9) ? S.p[1]+u*64 : (u<12) ? S.p[5]+(u-9)*64
                     : (u<15) ? S.p[9]+(u-12)*64 : S.p[14];
    wsF[OFF_b1P0 + i] = src[i&63];
    return;
  }
  i -= 1024;
  if (i < 256){
    int u = i>>4, n = i&15;
    const float* src = (u<9) ? S.p[3]+u*8 : (u<12) ? S.p[7]+(u-9)*8
                     : (u<15) ? S.p[11]+(u-12)*8 : S.p[16];
    wsF[OFF_b2P0 + i] = (n<8) ? src[n] : 0.f;
    return;
  }
  i -= 256;
  if (i < 960){    // b1P1 natural [u][64]
    int u = i>>6;
    const float* src = (u<9) ? S.p[19]+u*64 : (u<12) ? S.p[23]+(u-9)*64
                               : S.p[27]+(u-12)*64;
    wsF[OFF_b1P1 + i] = src[i&63];
    return;
  }
  i -= 960;
  if (i < 240){
    int u = i>>4, n = i&15;
    const float* src = (u<9) ? S.p[21]+u*8 : (u<12) ? S.p[25]+(u-9)*8
                               : S.p[29]+(u-12)*8;
    wsF[OFF_b2P1 + i] = (n<8) ? src[n] : 0.f;
    return;
  }
  i -= 240;
  if (i < 144){ wsF[OFF_G0W3 + i] = S.p[12][i]; return; }
  i -= 144;
  if (i < 96){ wsF[OFF_SG0W3 + i] = S.p[17][i]; return; }
  i -= 96;
  if (i < 144){ wsF[OFF_G1W3 + i] = S.p[30][i]; return; }
  i -= 144;
  if (i < 24){ wsF[OFF_TW + i] = S.p[31][i]; return; }
  i -= 24;
  if (i < 3){ wsF[OFF_Tb + i] = S.p[32][i]; return; }
  i -= 3;
  { // TWH: [t][w] = pkh2(TW[t][2w], TW[t][2w+1])
    int t = i>>2, w = i&3;
    wsU[OFF_TWH + i] = pkh2(S.p[31][t*8 + 2*w], S.p[31][t*8 + 2*w + 1]);
  }
}

template<int N>
__device__ __forceinline__ void softmaxT(float (&v)[N]){
  float m = v[0];
  #pragma unroll
  for (int i=1;i<N;i++) m = fmaxf(m, v[i]);
  float s = 0.f;
  #pragma unroll
  for (int i=0;i<N;i++){ v[i] = __expf(v[i]-m); s += v[i]; }
  float inv = 1.f/s;
  #pragma unroll
  for (int i=0;i<N;i++) v[i] *= inv;
}

__global__ __launch_bounds__(NT, 4) void ple_kernel(
    const float* __restrict__ emb, const int* __restrict__ cat,
    const u32* __restrict__ wsU, const float* __restrict__ P,
    float* __restrict__ out, int Btot)
{
  // LDS (u32): xsA [64e][52] (x f16 pairs), aliased as l1in [64e][36].
  // obT [64e][68]: unit-major, u16 col = u*8 + n (u=0..15, n=0..7).
  __shared__ u32 S_[7680];
  u32* xsA = S_;            // 3328
  u32* obT = S_ + 3328;     // 4352
  const int tid = threadIdx.x;
  const int e = tid & 63;
  const int su = __builtin_amdgcn_readfirstlane(tid >> 6);  // wave id 0..7
  const int lane = tid & 63;
  const int q = lane >> 4;
  const int c16 = lane & 15;

  // ---- phase 0: gather x -> xsA [e][52] f16 pairs, zero pad ----
  {
    const int eg = blockIdx.x*EPB + e;
    auto ldf = [&](int f){
      int idx = cat[eg*9 + f];
      const float* ep = emb + (long)idx*8;
      float4 a = *(const float4*)ep;
      float4 b = *(const float4*)(ep+4);
      uint4 w; w.x = pkh2(a.x,a.y); w.y = pkh2(a.z,a.w);
      w.z = pkh2(b.x,b.y); w.w = pkh2(b.z,b.w);
      *(uint4*)(xsA + e*52 + f*4) = w;
    };
    ldf(su);
    if (su == 0) ldf(8);
    if (su < 3) *(uint4*)(xsA + e*52 + 36 + su*4) = (uint4){0,0,0,0};
  }
  __syncthreads();

  // ---- phase 1: level-0, wave su owns units 2su, 2su+1 ----
  {
    #pragma unroll 1
    for (int k2 = 0; k2 < 2; k2++){
      const int u = su*2 + k2;
      half8 bf[3][4];
      #pragma unroll
      for (int s=0;s<3;s++)
        #pragma unroll
        for (int t=0;t<4;t++)
          bf[s][t] = *(const half8*)(wsU + W1F0 + (((u*3+s)*4+t)*64 + lane)*4);
      floatx4 bias[4];
      #pragma unroll
      for (int t=0;t<4;t++){
        float4 b4 = *(const float4*)(P + OFF_b1P0 + u*64 + t*16 + q*4);
        bias[t] = (floatx4){b4.x, b4.y, b4.z, b4.w};
      }
      float4 b2v = *(const float4*)(P + OFF_b2P0 + u*16 + q*4);
      half8 w2f[2];
      #pragma unroll
      for (int ks=0;ks<2;ks++)
        w2f[ks] = *(const half8*)(wsU + W2F0 + ((u*2+ks)*64 + lane)*4);

      #pragma unroll 1
      for (int m=0;m<4;m++){
        half8 af[3];
        #pragma unroll
        for (int s=0;s<3;s++)
          af[s] = *(const half8*)(xsA + (m*16 + c16)*52 + s*16 + q*4);
        floatx4 acc[4];
        #pragma unroll
        for (int t=0;t<4;t++) acc[t] = bias[t];
        #pragma unroll
        for (int s=0;s<3;s++)
          #pragma unroll
          for (int t=0;t<4;t++)
            acc[t] = __builtin_amdgcn_mfma_f32_16x16x32_f16(bf[s][t], af[s], acc[t], 0,0,0);
        // lane holds H[e=c16][h=t*16+q*4+r]; pack to W2-B frags
        floatx4 oc = (floatx4){b2v.x, b2v.y, b2v.z, b2v.w};
        #pragma unroll
        for (int ks=0;ks<2;ks++){
          u32 aw[4];
          aw[0] = pkh2(fmaxf(acc[2*ks  ][0],0.f), fmaxf(acc[2*ks  ][1],0.f));
          aw[1] = pkh2(fmaxf(acc[2*ks  ][2],0.f), fmaxf(acc[2*ks  ][3],0.f));
          aw[2] = pkh2(fmaxf(acc[2*ks+1][0],0.f), fmaxf(acc[2*ks+1][1],0.f));
          aw[3] = pkh2(fmaxf(acc[2*ks+1][2],0.f), fmaxf(acc[2*ks+1][3],0.f));
          half8 haf; __builtin_memcpy(&haf, aw, 16);
          oc = __builtin_amdgcn_mfma_f32_16x16x32_f16(w2f[ks], haf, oc, 0,0,0);
        }
        // lane holds O[e=c16][n=q*4+r]; q<2 covers n=0..7 -> one b64 store
        if (q < 2){
          uint2 ov;
          ov.x = pkh2(fmaxf(oc[0],0.f), fmaxf(oc[1],0.f));
          ov.y = pkh2(fmaxf(oc[2],0.f), fmaxf(oc[3],0.f));
          *(uint2*)(obT + (m*16 + c16)*68 + u*4 + q*2) = ov;
        }
      }
    }
  }
  __syncthreads();

  // ---- phase 2: level-0 gates + pk_fma mixing (waves 0..3 only) ----
  u32* l1in = xsA;
  if (su < 4){
    *(uint4*)(l1in + e*36 + 16 + su*4) = (uint4){0,0,0,0};
    float wv[12];
    {
      const int ug = (su<3) ? 12+su : 15;
      uint4 gw = *(const uint4*)(obT + e*68 + ug*4);
      float g8[8]; unp8(gw, g8);
      if (su < 3){
        float lg[6];
        #pragma unroll
        for (int m=0;m<6;m++){
          float s = 0.f;
          #pragma unroll
          for (int j=0;j<8;j++) s = fmaf(g8[j], P[OFF_G0W3 + su*48 + j*6 + m], s);
          lg[m] = s;
        }
        softmaxT<6>(lg);
        #pragma unroll
        for (int k=0;k<12;k++)
          wv[k] = (k<9) ? (((k/3)==su) ? lg[k%3] : 0.f) : lg[k-6];
      } else {
        float lw[12];
        #pragma unroll
        for (int m=0;m<12;m++){
          float s = 0.f;
          #pragma unroll
          for (int j=0;j<8;j++) s = fmaf(g8[j], P[OFF_SG0W3 + j*12 + m], s);
          lw[m] = s;
        }
        softmaxT<12>(lw);
        #pragma unroll
        for (int k=0;k<12;k++) wv[k] = lw[k];
      }
    }
    hv2 a01 = (hv2){0,0}, a23 = (hv2){0,0}, a45 = (hv2){0,0}, a67 = (hv2){0,0};
    #pragma unroll
    for (int u=0;u<12;u++){
      uint4 ow = *(const uint4*)(obT + e*68 + u*4);
      __fp16 wh = (__fp16)wv[u];
      hv2 wp = (hv2){wh, wh};
      a01 = u2h(ow.x)*wp + a01;
      a23 = u2h(ow.y)*wp + a23;
      a45 = u2h(ow.z)*wp + a45;
      a67 = u2h(ow.w)*wp + a67;
    }
    const int dst = (su<3) ? su*4 : 12;
    uint4 lw4; lw4.x = h2u(a01); lw4.y = h2u(a23);
    lw4.z = h2u(a45); lw4.w = h2u(a67);
    *(uint4*)(l1in + e*36 + dst) = lw4;
  }
  __syncthreads();

  // ---- phase 3: level-1, wave su owns units 2su, 2su+1 (u<15) ----
  {
    #pragma unroll 1
    for (int k2=0;k2<2;k2++){
      const int u = su*2 + k2;
      if (u >= 15) break;
      const int base_u = (u<9) ? (u/3)*4 : ((u<12) ? 12 : (u-12)*4);
      const int aoff = (q==0) ? base_u : (16 + q*4);   // q>=1 -> zeros
      half8 bf1[4];
      #pragma unroll
      for (int t=0;t<4;t++)
        bf1[t] = *(const half8*)(wsU + W1F1 + ((u*4+t)*64 + lane)*4);
      floatx4 bias[4];
      #pragma unroll
      for (int t=0;t<4;t++){
        float4 b4 = *(const float4*)(P + OFF_b1P1 + u*64 + t*16 + q*4);
        bias[t] = (floatx4){b4.x, b4.y, b4.z, b4.w};
      }
      float4 b2v = *(const float4*)(P + OFF_b2P1 + u*16 + q*4);
      half8 w2f[2];
      #pragma unroll
      for (int ks=0;ks<2;ks++)
        w2f[ks] = *(const half8*)(wsU + W2F1 + ((u*2+ks)*64 + lane)*4);

      #pragma unroll 1
      for (int m=0;m<4;m++){
        half8 af = *(const half8*)(l1in + (m*16 + c16)*36 + aoff);
        floatx4 acc[4];
        #pragma unroll
        for (int t=0;t<4;t++) acc[t] = bias[t];
        #pragma unroll
        for (int t=0;t<4;t++)
          acc[t] = __builtin_amdgcn_mfma_f32_16x16x32_f16(bf1[t], af, acc[t], 0,0,0);
        floatx4 oc = (floatx4){b2v.x, b2v.y, b2v.z, b2v.w};
        #pragma unroll
        for (int ks=0;ks<2;ks++){
          u32 aw[4];
          aw[0] = pkh2(fmaxf(acc[2*ks  ][0],0.f), fmaxf(acc[2*ks  ][1],0.f));
          aw[1] = pkh2(fmaxf(acc[2*ks  ][2],0.f), fmaxf(acc[2*ks  ][3],0.f));
          aw[2] = pkh2(fmaxf(acc[2*ks+1][0],0.f), fmaxf(acc[2*ks+1][1],0.f));
          aw[3] = pkh2(fmaxf(acc[2*ks+1][2],0.f), fmaxf(acc[2*ks+1][3],0.f));
          half8 haf; __builtin_memcpy(&haf, aw, 16);
          oc = __builtin_amdgcn_mfma_f32_16x16x32_f16(w2f[ks], haf, oc, 0,0,0);
        }
        if (q < 2){
          uint2 ov;
          ov.x = pkh2(fmaxf(oc[0],0.f), fmaxf(oc[1],0.f));
          ov.y = pkh2(fmaxf(oc[2],0.f), fmaxf(oc[3],0.f));
          *(uint2*)(obT + (m*16 + c16)*68 + u*4 + q*2) = ov;
        }
      }
    }
  }
  __syncthreads();

  // ---- phase 4: level-1 gates + pk_fma mixing + towers (waves 0..2) ----
  if (su < 3){
    const int t = su;
    uint4 gw = *(const uint4*)(obT + e*68 + (12+t)*4);
    float g8[8]; unp8(gw, g8);
    float lg[6];
    #pragma unroll
    for (int m=0;m<6;m++){
      float s = 0.f;
      #pragma unroll
      for (int j=0;j<8;j++) s = fmaf(g8[j], P[OFF_G1W3 + t*48 + j*6 + m], s);
      lg[m] = s;
    }
    softmaxT<6>(lg);
    float wv[12];
    #pragma unroll
    for (int k=0;k<12;k++)
      wv[k] = (k<9) ? (((k/3)==t) ? lg[k%3] : 0.f) : lg[k-6];
    hv2 a01 = (hv2){0,0}, a23 = (hv2){0,0}, a45 = (hv2){0,0}, a67 = (hv2){0,0};
    #pragma unroll
    for (int u=0;u<12;u++){
      uint4 ow = *(const uint4*)(obT + e*68 + u*4);
      __fp16 wh = (__fp16)wv[u];
      hv2 wp = (hv2){wh, wh};
      a01 = u2h(ow.x)*wp + a01;
      a23 = u2h(ow.y)*wp + a23;
      a45 = u2h(ow.z)*wp + a45;
      a67 = u2h(ow.w)*wp + a67;
    }
    float s = P[OFF_Tb + t];
    s = dot2(h2u(a01), wsU[OFF_TWH + t*4 + 0], s);
    s = dot2(h2u(a23), wsU[OFF_TWH + t*4 + 1], s);
    s = dot2(h2u(a45), wsU[OFF_TWH + t*4 + 2], s);
    s = dot2(h2u(a67), wsU[OFF_TWH + t*4 + 3], s);
    out[t*Btot + blockIdx.x*EPB + e] = 1.f/(1.f + __expf(-s));
  }
}

extern "C" void kernel_launch(void* const* d_in, const int* in_sizes, int n_in,
                              void* d_out, int out_size, void* d_ws, size_t ws_size,
                              hipStream_t stream)
{
  const float* emb = (const float*)d_in[0];
  const int* cat = (const int*)d_in[34];
  float* out = (float*)d_out;
  u32* wsU = (u32*)d_ws;
  float* wsF = (float*)d_ws;
  PSrc S;
  for (int k=0;k<33;k++) S.p[k] = (const float*)d_in[k+1];
  const int B = in_sizes[34] / 9;   // 131072

  cvt_kernel<<<(CVT_TOTAL+255)/256, 256, 0, stream>>>(S, wsU, wsF);
  ple_kernel<<<B/EPB, NT, 0, stream>>>(emb, cat, wsU, wsF, out, B);
}

// Round 15
// 176.698 us; speedup vs baseline: 1.0567x; 1.0567x over previous
//
#include <hip/hip_runtime.h>

// PLELayer round-15: revert r14's NT=512 (barrier-convoy regression:
// occupancy counter stayed ~36%, dur +5us -> latency is barrier-structure
// bound, not wave-count bound). Base = r13 (65.9us) plus:
// (1) f16-side relu: pack with v_cvt_pkrtz first, then v_pk_max_f16
//     (epilogue 30->20 VALU per unit-m; round-then-clamp == clamp-then-
//     round for relu).
// (2) #pragma unroll 2 on the m-loops: overlap m+1 af-load/W1-MFMAs with
//     m's epilogue (serial chain was exposed). VGPR watch: 60 -> ~90-100,
//     cap 128 (launch_bounds(256,4)); WRITE_SIZE is the spill tripwire.

#define NT 256
#define EPB 64

typedef unsigned short u16;
typedef unsigned int u32;
typedef __fp16 hv2 __attribute__((ext_vector_type(2)));
typedef __fp16 half8 __attribute__((ext_vector_type(8)));
typedef __attribute__((ext_vector_type(4))) float floatx4;

__device__ __forceinline__ u32 pkh2(float a, float b){
  hv2 v = __builtin_amdgcn_cvt_pkrtz(a, b);
  u32 r; __builtin_memcpy(&r, &v, 4); return r;
}
__device__ __forceinline__ float h2f(u16 v){
  __fp16 h; __builtin_memcpy(&h, &v, 2); return (float)h;
}
__device__ __forceinline__ hv2 u2h(u32 w){ hv2 v; __builtin_memcpy(&v, &w, 4); return v; }
__device__ __forceinline__ u32 h2u(hv2 v){ u32 w; __builtin_memcpy(&w, &v, 4); return w; }
__device__ __forceinline__ float dot2(u32 a, u32 b, float c){
  return __builtin_amdgcn_fdot2(u2h(a), u2h(b), c, false);
}
// pack two f32 then relu in f16 (v_cvt_pkrtz + v_pk_max_f16)
__device__ __forceinline__ u32 pkrelu(float a, float b){
  hv2 v = __builtin_amdgcn_cvt_pkrtz(a, b);
  hv2 z = (hv2){(__fp16)0.f, (__fp16)0.f};
  return h2u(__builtin_elementwise_max(v, z));
}
__device__ __forceinline__ void unp8(uint4 gw, float g8[8]){
  g8[0]=h2f((u16)(gw.x&0xffffu)); g8[1]=h2f((u16)(gw.x>>16));
  g8[2]=h2f((u16)(gw.y&0xffffu)); g8[3]=h2f((u16)(gw.y>>16));
  g8[4]=h2f((u16)(gw.z&0xffffu)); g8[5]=h2f((u16)(gw.z>>16));
  g8[6]=h2f((u16)(gw.w&0xffffu)); g8[7]=h2f((u16)(gw.w>>16));
}

// ---- ws layout ----
#define W1F0 0          // [16u][3s][4t][64l][4]  = 49152 u32 (f16 pairs)
#define W2F0 49152      // [16u][2ks][64l][4]     =  8192 (h'(q,ks,j) perm)
#define W1F1 57344      // [15u][4t][64l][4]      = 15360
#define W2F1 72704      // [15u][2ks][64l][4]     =  7680 (h' perm)
#define OFF_b1P0 80384  // [16][64] natural
#define OFF_b2P0 81408  // [16][16] cols 8..15 zero
#define OFF_b1P1 81664  // [15][64] natural
#define OFF_b2P1 82624  // [15][16] cols 8..15 zero
#define OFF_G0W3 82864  // [3][8][6]
#define OFF_SG0W3 83008 // [8][12]
#define OFF_G1W3 83104  // [3][8][6]
#define OFF_TW   83248  // [3][8] fp32 (unused by kernel now, kept)
#define OFF_Tb   83272  // [3]
#define OFF_TWH  83275  // [3][4] u32: packed f16 pairs of tower_W
#define CVT_TOTAL 83287

struct PSrc { const float* p[33]; };

__global__ void cvt_kernel(PSrc S, u32* __restrict__ wsU, float* __restrict__ wsF){
  int i = blockIdx.x*256 + threadIdx.x;
  if (i >= CVT_TOTAL) return;
  if (i < 49152){  // W1F0: lane holds W1[k=s*32+q*8+j][h=t*16+c16], k>=72 -> 0
    int j2 = i & 3, l = (i>>2)&63, tt = (i>>8)&3;
    int rest = i >> 10; int s = rest % 3, u = rest / 3;
    int k0 = s*32 + (l>>4)*8 + 2*j2;
    int h  = tt*16 + (l&15);
    const float* src = (u<9)  ? S.p[0]  + (u*72)*64
                     : (u<12) ? S.p[4]  + ((u-9)*72)*64
                     : (u<15) ? S.p[8]  + ((u-12)*72)*64
                              : S.p[13];
    float lo = (k0   < 72) ? src[(k0  )*64 + h] : 0.f;
    float hi = (k0+1 < 72) ? src[(k0+1)*64 + h] : 0.f;
    wsU[i] = pkh2(lo, hi);
    return;
  }
  i -= 49152;
  if (i < 8192){   // W2F0: W2[h'(q,ks,j)][n=l&15], n>=8 -> 0
    int j2 = i & 3, l = (i>>2)&63, ks = (i>>8)&1, u = i>>9;
    int q = l >> 4, n = l & 15;
    int h0 = (2*ks + ((2*j2)>>2))*16 + q*4 + ((2*j2)&3);
    const float* src = (u<9)  ? S.p[2]  + u*512
                     : (u<12) ? S.p[6]  + (u-9)*512
                     : (u<15) ? S.p[10] + (u-12)*512
                              : S.p[15];
    float lo = (n<8) ? src[h0*8 + n] : 0.f;
    float hi = (n<8) ? src[(h0+1)*8 + n] : 0.f;
    wsU[W2F0 + i] = pkh2(lo, hi);
    return;
  }
  i -= 8192;
  if (i < 15360){  // W1F1: lane holds W1[k=q*8+j][h=t*16+c16], k>=8 -> 0
    int j2 = i & 3, l = (i>>2)&63, tt = (i>>8)&3, u = i>>10;
    int k0 = (l>>4)*8 + 2*j2;
    int n = tt*16 + (l&15);
    const float* src = (u<9) ? S.p[18] + (u*8)*64
                     : (u<12) ? S.p[22] + ((u-9)*8)*64
                              : S.p[26] + ((u-12)*8)*64;
    float lo = (k0   < 8) ? src[(k0  )*64 + n] : 0.f;
    float hi = (k0+1 < 8) ? src[(k0+1)*64 + n] : 0.f;
    wsU[W1F1 + i] = pkh2(lo, hi);
    return;
  }
  i -= 15360;
  if (i < 7680){   // W2F1: h'(q,ks,j) permutation, n>=8 -> 0
    int j2 = i & 3, l = (i>>2)&63, ks = (i>>8)&1, u = i>>9;
    int q = l >> 4, n = l & 15;
    int h0 = (2*ks + ((2*j2)>>2))*16 + q*4 + ((2*j2)&3);
    const float* src = (u<9) ? S.p[20] + u*512
                     : (u<12) ? S.p[24] + (u-9)*512
                              : S.p[28] + (u-12)*512;
    float lo = (n<8) ? src[h0*8 + n] : 0.f;
    float hi = (n<8) ? src[(h0+1)*8 + n] : 0.f;
    wsU[W2F1 + i] = pkh2(lo, hi);
    return;
  }
  i -= 7680;
  if (i < 1024){   // b1P0 natural [u][64]
    int u = i>>6;
    const float* src = (u<9) ? S.p[1]+u*64 : (u<12) ? S.p[5]+(u-9)*64
                     : (u<15) ? S.p[9]+(u-12)*64 : S.p[14];
    wsF[OFF_b1P0 + i] = src[i&63];
    return;
  }
  i -= 1024;
  if (i < 256){
    int u = i>>4, n = i&15;
    const float* src = (u<9) ? S.p[3]+u*8 : (u<12) ? S.p[7]+(u-9)*8
                     : (u<15) ? S.p[11]+(u-12)*8 : S.p[16];
    wsF[OFF_b2P0 + i] = (n<8) ? src[n] : 0.f;
    return;
  }
  i -= 256;
  if (i < 960){    // b1P1 natural [u][64]
    int u = i>>6;
    const float* src = (u<9) ? S.p[19]+u*64 : (u<12) ? S.p[23]+(u-9)*64
                               : S.p[27]+(u-12)*64;
    wsF[OFF_b1P1 + i] = src[i&63];
    return;
  }
  i -= 960;
  if (i < 240){
    int u = i>>4, n = i&15;
    const float* src = (u<9) ? S.p[21]+u*8 : (u<12) ? S.p[25]+(u-9)*8
                               : S.p[29]+(u-12)*8;
    wsF[OFF_b2P1 + i] = (n<8) ? src[n] : 0.f;
    return;
  }
  i -= 240;
  if (i < 144){ wsF[OFF_G0W3 + i] = S.p[12][i]; return; }
  i -= 144;
  if (i < 96){ wsF[OFF_SG0W3 + i] = S.p[17][i]; return; }
  i -= 96;
  if (i < 144){ wsF[OFF_G1W3 + i] = S.p[30][i]; return; }
  i -= 144;
  if (i < 24){ wsF[OFF_TW + i] = S.p[31][i]; return; }
  i -= 24;
  if (i < 3){ wsF[OFF_Tb + i] = S.p[32][i]; return; }
  i -= 3;
  { // TWH: [t][w] = pkh2(TW[t][2w], TW[t][2w+1])
    int t = i>>2, w = i&3;
    wsU[OFF_TWH + i] = pkh2(S.p[31][t*8 + 2*w], S.p[31][t*8 + 2*w + 1]);
  }
}

template<int N>
__device__ __forceinline__ void softmaxT(float (&v)[N]){
  float m = v[0];
  #pragma unroll
  for (int i=1;i<N;i++) m = fmaxf(m, v[i]);
  float s = 0.f;
  #pragma unroll
  for (int i=0;i<N;i++){ v[i] = __expf(v[i]-m); s += v[i]; }
  float inv = 1.f/s;
  #pragma unroll
  for (int i=0;i<N;i++) v[i] *= inv;
}

__global__ __launch_bounds__(NT, 4) void ple_kernel(
    const float* __restrict__ emb, const int* __restrict__ cat,
    const u32* __restrict__ wsU, const float* __restrict__ P,
    float* __restrict__ out, int Btot)
{
  // LDS (u32): xsA [64e][52] (x f16 pairs), aliased as l1in [64e][36].
  // obT [64e][68]: unit-major, u16 col = u*8 + n (u=0..15, n=0..7).
  __shared__ u32 S_[7680];
  u32* xsA = S_;            // 3328
  u32* obT = S_ + 3328;     // 4352
  const int tid = threadIdx.x;
  const int e = tid & 63;
  const int su = __builtin_amdgcn_readfirstlane(tid >> 6);
  const int lane = tid & 63;
  const int q = lane >> 4;
  const int c16 = lane & 15;

  // ---- phase 0: gather x -> xsA [e][52] f16 pairs, zero pad ----
  {
    const int eg = blockIdx.x*EPB + e;
    auto ldf = [&](int f){
      int idx = cat[eg*9 + f];
      const float* ep = emb + (long)idx*8;
      float4 a = *(const float4*)ep;
      float4 b = *(const float4*)(ep+4);
      uint4 w; w.x = pkh2(a.x,a.y); w.y = pkh2(a.z,a.w);
      w.z = pkh2(b.x,b.y); w.w = pkh2(b.z,b.w);
      *(uint4*)(xsA + e*52 + f*4) = w;
    };
    ldf(su); ldf(su+4);
    if (su == 0) ldf(8);
    *(uint4*)(xsA + e*52 + 36 + su*4) = (uint4){0,0,0,0};
  }
  __syncthreads();

  // ---- phase 1: level-0, both GEMMs operand-swapped ----
  {
    #pragma unroll 1
    for (int k4 = 0; k4 < 4; k4++){
      const int u = su*4 + k4;
      half8 bf[3][4];
      #pragma unroll
      for (int s=0;s<3;s++)
        #pragma unroll
        for (int t=0;t<4;t++)
          bf[s][t] = *(const half8*)(wsU + W1F0 + (((u*3+s)*4+t)*64 + lane)*4);
      floatx4 bias[4];
      #pragma unroll
      for (int t=0;t<4;t++){
        float4 b4 = *(const float4*)(P + OFF_b1P0 + u*64 + t*16 + q*4);
        bias[t] = (floatx4){b4.x, b4.y, b4.z, b4.w};
      }
      float4 b2v = *(const float4*)(P + OFF_b2P0 + u*16 + q*4);
      half8 w2f[2];
      #pragma unroll
      for (int ks=0;ks<2;ks++)
        w2f[ks] = *(const half8*)(wsU + W2F0 + ((u*2+ks)*64 + lane)*4);

      #pragma unroll 2
      for (int m=0;m<4;m++){
        half8 af[3];
        #pragma unroll
        for (int s=0;s<3;s++)
          af[s] = *(const half8*)(xsA + (m*16 + c16)*52 + s*16 + q*4);
        floatx4 acc[4];
        #pragma unroll
        for (int t=0;t<4;t++) acc[t] = bias[t];
        #pragma unroll
        for (int s=0;s<3;s++)
          #pragma unroll
          for (int t=0;t<4;t++)
            acc[t] = __builtin_amdgcn_mfma_f32_16x16x32_f16(bf[s][t], af[s], acc[t], 0,0,0);
        // lane holds H[e=c16][h=t*16+q*4+r]; pack + f16-relu to W2-B frags
        floatx4 oc = (floatx4){b2v.x, b2v.y, b2v.z, b2v.w};
        #pragma unroll
        for (int ks=0;ks<2;ks++){
          u32 aw[4];
          aw[0] = pkrelu(acc[2*ks  ][0], acc[2*ks  ][1]);
          aw[1] = pkrelu(acc[2*ks  ][2], acc[2*ks  ][3]);
          aw[2] = pkrelu(acc[2*ks+1][0], acc[2*ks+1][1]);
          aw[3] = pkrelu(acc[2*ks+1][2], acc[2*ks+1][3]);
          half8 haf; __builtin_memcpy(&haf, aw, 16);
          oc = __builtin_amdgcn_mfma_f32_16x16x32_f16(w2f[ks], haf, oc, 0,0,0);
        }
        // lane holds O[e=c16][n=q*4+r]; q<2 covers n=0..7 -> one b64 store
        if (q < 2){
          uint2 ov;
          ov.x = pkrelu(oc[0], oc[1]);
          ov.y = pkrelu(oc[2], oc[3]);
          *(uint2*)(obT + (m*16 + c16)*68 + u*4 + q*2) = ov;
        }
      }
    }
  }
  __syncthreads();

  // ---- phase 2: level-0 gates + pk_fma mixing -> l1in [64e][36] ----
  u32* l1in = xsA;
  *(uint4*)(l1in + e*36 + 16 + su*4) = (uint4){0,0,0,0};
  {
    float wv[12];
    {
      const int ug = (su<3) ? 12+su : 15;
      uint4 gw = *(const uint4*)(obT + e*68 + ug*4);
      float g8[8]; unp8(gw, g8);
      if (su < 3){
        float lg[6];
        #pragma unroll
        for (int m=0;m<6;m++){
          float s = 0.f;
          #pragma unroll
          for (int j=0;j<8;j++) s = fmaf(g8[j], P[OFF_G0W3 + su*48 + j*6 + m], s);
          lg[m] = s;
        }
        softmaxT<6>(lg);
        #pragma unroll
        for (int k=0;k<12;k++)
          wv[k] = (k<9) ? (((k/3)==su) ? lg[k%3] : 0.f) : lg[k-6];
      } else {
        float lw[12];
        #pragma unroll
        for (int m=0;m<12;m++){
          float s = 0.f;
          #pragma unroll
          for (int j=0;j<8;j++) s = fmaf(g8[j], P[OFF_SG0W3 + j*12 + m], s);
          lw[m] = s;
        }
        softmaxT<12>(lw);
        #pragma unroll
        for (int k=0;k<12;k++) wv[k] = lw[k];
      }
    }
    hv2 a01 = (hv2){0,0}, a23 = (hv2){0,0}, a45 = (hv2){0,0}, a67 = (hv2){0,0};
    #pragma unroll
    for (int u=0;u<12;u++){
      uint4 ow = *(const uint4*)(obT + e*68 + u*4);
      __fp16 wh = (__fp16)wv[u];
      hv2 wp = (hv2){wh, wh};
      a01 = u2h(ow.x)*wp + a01;
      a23 = u2h(ow.y)*wp + a23;
      a45 = u2h(ow.z)*wp + a45;
      a67 = u2h(ow.w)*wp + a67;
    }
    const int dst = (su<3) ? su*4 : 12;
    uint4 lw4; lw4.x = h2u(a01); lw4.y = h2u(a23);
    lw4.z = h2u(a45); lw4.w = h2u(a67);
    *(uint4*)(l1in + e*36 + dst) = lw4;
  }
  __syncthreads();

  // ---- phase 3: level-1, operand-swapped GEMMs ----
  {
    #pragma unroll 1
    for (int k4=0;k4<4;k4++){
      const int u = su*4 + k4;
      if (u >= 15) break;
      const int base_u = (u<9) ? (u/3)*4 : ((u<12) ? 12 : (u-12)*4);
      const int aoff = (q==0) ? base_u : (16 + q*4);   // q>=1 -> zeros
      half8 bf1[4];
      #pragma unroll
      for (int t=0;t<4;t++)
        bf1[t] = *(const half8*)(wsU + W1F1 + ((u*4+t)*64 + lane)*4);
      floatx4 bias[4];
      #pragma unroll
      for (int t=0;t<4;t++){
        float4 b4 = *(const float4*)(P + OFF_b1P1 + u*64 + t*16 + q*4);
        bias[t] = (floatx4){b4.x, b4.y, b4.z, b4.w};
      }
      float4 b2v = *(const float4*)(P + OFF_b2P1 + u*16 + q*4);
      half8 w2f[2];
      #pragma unroll
      for (int ks=0;ks<2;ks++)
        w2f[ks] = *(const half8*)(wsU + W2F1 + ((u*2+ks)*64 + lane)*4);

      #pragma unroll 2
      for (int m=0;m<4;m++){
        half8 af = *(const half8*)(l1in + (m*16 + c16)*36 + aoff);
        floatx4 acc[4];
        #pragma unroll
        for (int t=0;t<4;t++) acc[t] = bias[t];
        #pragma unroll
        for (int t=0;t<4;t++)
          acc[t] = __builtin_amdgcn_mfma_f32_16x16x32_f16(bf1[t], af, acc[t], 0,0,0);
        floatx4 oc = (floatx4){b2v.x, b2v.y, b2v.z, b2v.w};
        #pragma unroll
        for (int ks=0;ks<2;ks++){
          u32 aw[4];
          aw[0] = pkrelu(acc[2*ks  ][0], acc[2*ks  ][1]);
          aw[1] = pkrelu(acc[2*ks  ][2], acc[2*ks  ][3]);
          aw[2] = pkrelu(acc[2*ks+1][0], acc[2*ks+1][1]);
          aw[3] = pkrelu(acc[2*ks+1][2], acc[2*ks+1][3]);
          half8 haf; __builtin_memcpy(&haf, aw, 16);
          oc = __builtin_amdgcn_mfma_f32_16x16x32_f16(w2f[ks], haf, oc, 0,0,0);
        }
        if (q < 2){
          uint2 ov;
          ov.x = pkrelu(oc[0], oc[1]);
          ov.y = pkrelu(oc[2], oc[3]);
          *(uint2*)(obT + (m*16 + c16)*68 + u*4 + q*2) = ov;
        }
      }
    }
  }
  __syncthreads();

  // ---- phase 4: level-1 gates + pk_fma mixing + towers ----
  if (su < 3){
    const int t = su;
    uint4 gw = *(const uint4*)(obT + e*68 + (12+t)*4);
    float g8[8]; unp8(gw, g8);
    float lg[6];
    #pragma unroll
    for (int m=0;m<6;m++){
      float s = 0.f;
      #pragma unroll
      for (int j=0;j<8;j++) s = fmaf(g8[j], P[OFF_G1W3 + t*48 + j*6 + m], s);
      lg[m] = s;
    }
    softmaxT<6>(lg);
    float wv[12];
    #pragma unroll
    for (int k=0;k<12;k++)
      wv[k] = (k<9) ? (((k/3)==t) ? lg[k%3] : 0.f) : lg[k-6];
    hv2 a01 = (hv2){0,0}, a23 = (hv2){0,0}, a45 = (hv2){0,0}, a67 = (hv2){0,0};
    #pragma unroll
    for (int u=0;u<12;u++){
      uint4 ow = *(const uint4*)(obT + e*68 + u*4);
      __fp16 wh = (__fp16)wv[u];
      hv2 wp = (hv2){wh, wh};
      a01 = u2h(ow.x)*wp + a01;
      a23 = u2h(ow.y)*wp + a23;
      a45 = u2h(ow.z)*wp + a45;
      a67 = u2h(ow.w)*wp + a67;
    }
    float s = P[OFF_Tb + t];
    s = dot2(h2u(a01), wsU[OFF_TWH + t*4 + 0], s);
    s = dot2(h2u(a23), wsU[OFF_TWH + t*4 + 1], s);
    s = dot2(h2u(a45), wsU[OFF_TWH + t*4 + 2], s);
    s = dot2(h2u(a67), wsU[OFF_TWH + t*4 + 3], s);
    out[t*Btot + blockIdx.x*EPB + e] = 1.f/(1.f + __expf(-s));
  }
}

extern "C" void kernel_launch(void* const* d_in, const int* in_sizes, int n_in,
                              void* d_out, int out_size, void* d_ws, size_t ws_size,
                              hipStream_t stream)
{
  const float* emb = (const float*)d_in[0];
  const int* cat = (const int*)d_in[34];
  float* out = (float*)d_out;
  u32* wsU = (u32*)d_ws;
  float* wsF = (float*)d_ws;
  PSrc S;
  for (int k=0;k<33;k++) S.p[k] = (const float*)d_in[k+1];
  const int B = in_sizes[34] / 9;   // 131072

  cvt_kernel<<<(CVT_TOTAL+255)/256, 256, 0, stream>>>(S, wsU, wsF);
  ple_kernel<<<B/EPB, NT, 0, stream>>>(emb, cat, wsU, wsF, out, B);
}

// Round 16
// 176.525 us; speedup vs baseline: 1.0577x; 1.0010x over previous
//
#include <hip/hip_runtime.h>

// PLELayer round-16: r15 + full m-unroll. r15 post-mortem: VALU 33%,
// MFMA 28.5%, ~40% of cycles neither pipe issues -> dependent-chain
// latency with scheduler-visible ILP as the lever (unroll 2 gave 10%).
// (1) #pragma unroll 4 on phase-1/3 m-loops: all 4 unit-m chains visible;
//     70 spare VGPRs (56 used / 128 cap) let the scheduler interleave.
//     WRITE_SIZE is the spill tripwire.
// (2) field-8 gather spread across waves (was all on wave 0).
// Everything else identical to r15.

#define NT 256
#define EPB 64

typedef unsigned short u16;
typedef unsigned int u32;
typedef __fp16 hv2 __attribute__((ext_vector_type(2)));
typedef __fp16 half8 __attribute__((ext_vector_type(8)));
typedef __attribute__((ext_vector_type(4))) float floatx4;

__device__ __forceinline__ u32 pkh2(float a, float b){
  hv2 v = __builtin_amdgcn_cvt_pkrtz(a, b);
  u32 r; __builtin_memcpy(&r, &v, 4); return r;
}
__device__ __forceinline__ float h2f(u16 v){
  __fp16 h; __builtin_memcpy(&h, &v, 2); return (float)h;
}
__device__ __forceinline__ hv2 u2h(u32 w){ hv2 v; __builtin_memcpy(&v, &w, 4); return v; }
__device__ __forceinline__ u32 h2u(hv2 v){ u32 w; __builtin_memcpy(&w, &v, 4); return w; }
__device__ __forceinline__ float dot2(u32 a, u32 b, float c){
  return __builtin_amdgcn_fdot2(u2h(a), u2h(b), c, false);
}
// pack two f32 then relu in f16 (v_cvt_pkrtz + v_pk_max_f16)
__device__ __forceinline__ u32 pkrelu(float a, float b){
  hv2 v = __builtin_amdgcn_cvt_pkrtz(a, b);
  hv2 z = (hv2){(__fp16)0.f, (__fp16)0.f};
  return h2u(__builtin_elementwise_max(v, z));
}
__device__ __forceinline__ void unp8(uint4 gw, float g8[8]){
  g8[0]=h2f((u16)(gw.x&0xffffu)); g8[1]=h2f((u16)(gw.x>>16));
  g8[2]=h2f((u16)(gw.y&0xffffu)); g8[3]=h2f((u16)(gw.y>>16));
  g8[4]=h2f((u16)(gw.z&0xffffu)); g8[5]=h2f((u16)(gw.z>>16));
  g8[6]=h2f((u16)(gw.w&0xffffu)); g8[7]=h2f((u16)(gw.w>>16));
}

// ---- ws layout ----
#define W1F0 0          // [16u][3s][4t][64l][4]  = 49152 u32 (f16 pairs)
#define W2F0 49152      // [16u][2ks][64l][4]     =  8192 (h'(q,ks,j) perm)
#define W1F1 57344      // [15u][4t][64l][4]      = 15360
#define W2F1 72704      // [15u][2ks][64l][4]     =  7680 (h' perm)
#define OFF_b1P0 80384  // [16][64] natural
#define OFF_b2P0 81408  // [16][16] cols 8..15 zero
#define OFF_b1P1 81664  // [15][64] natural
#define OFF_b2P1 82624  // [15][16] cols 8..15 zero
#define OFF_G0W3 82864  // [3][8][6]
#define OFF_SG0W3 83008 // [8][12]
#define OFF_G1W3 83104  // [3][8][6]
#define OFF_TW   83248  // [3][8] fp32 (unused by kernel now, kept)
#define OFF_Tb   83272  // [3]
#define OFF_TWH  83275  // [3][4] u32: packed f16 pairs of tower_W
#define CVT_TOTAL 83287

struct PSrc { const float* p[33]; };

__global__ void cvt_kernel(PSrc S, u32* __restrict__ wsU, float* __restrict__ wsF){
  int i = blockIdx.x*256 + threadIdx.x;
  if (i >= CVT_TOTAL) return;
  if (i < 49152){  // W1F0: lane holds W1[k=s*32+q*8+j][h=t*16+c16], k>=72 -> 0
    int j2 = i & 3, l = (i>>2)&63, tt = (i>>8)&3;
    int rest = i >> 10; int s = rest % 3, u = rest / 3;
    int k0 = s*32 + (l>>4)*8 + 2*j2;
    int h  = tt*16 + (l&15);
    const float* src = (u<9)  ? S.p[0]  + (u*72)*64
                     : (u<12) ? S.p[4]  + ((u-9)*72)*64
                     : (u<15) ? S.p[8]  + ((u-12)*72)*64
                              : S.p[13];
    float lo = (k0   < 72) ? src[(k0  )*64 + h] : 0.f;
    float hi = (k0+1 < 72) ? src[(k0+1)*64 + h] : 0.f;
    wsU[i] = pkh2(lo, hi);
    return;
  }
  i -= 49152;
  if (i < 8192){   // W2F0: W2[h'(q,ks,j)][n=l&15], n>=8 -> 0
    int j2 = i & 3, l = (i>>2)&63, ks = (i>>8)&1, u = i>>9;
    int q = l >> 4, n = l & 15;
    int h0 = (2*ks + ((2*j2)>>2))*16 + q*4 + ((2*j2)&3);
    const float* src = (u<9)  ? S.p[2]  + u*512
                     : (u<12) ? S.p[6]  + (u-9)*512
                     : (u<15) ? S.p[10] + (u-12)*512
                              : S.p[15];
    float lo = (n<8) ? src[h0*8 + n] : 0.f;
    float hi = (n<8) ? src[(h0+1)*8 + n] : 0.f;
    wsU[W2F0 + i] = pkh2(lo, hi);
    return;
  }
  i -= 8192;
  if (i < 15360){  // W1F1: lane holds W1[k=q*8+j][h=t*16+c16], k>=8 -> 0
    int j2 = i & 3, l = (i>>2)&63, tt = (i>>8)&3, u = i>>10;
    int k0 = (l>>4)*8 + 2*j2;
    int n = tt*16 + (l&15);
    const float* src = (u<9) ? S.p[18] + (u*8)*64
                     : (u<12) ? S.p[22] + ((u-9)*8)*64
                              : S.p[26] + ((u-12)*8)*64;
    float lo = (k0   < 8) ? src[(k0  )*64 + n] : 0.f;
    float hi = (k0+1 < 8) ? src[(k0+1)*64 + n] : 0.f;
    wsU[W1F1 + i] = pkh2(lo, hi);
    return;
  }
  i -= 15360;
  if (i < 7680){   // W2F1: h'(q,ks,j) permutation, n>=8 -> 0
    int j2 = i & 3, l = (i>>2)&63, ks = (i>>8)&1, u = i>>9;
    int q = l >> 4, n = l & 15;
    int h0 = (2*ks + ((2*j2)>>2))*16 + q*4 + ((2*j2)&3);
    const float* src = (u<9) ? S.p[20] + u*512
                     : (u<12) ? S.p[24] + (u-9)*512
                              : S.p[28] + (u-12)*512;
    float lo = (n<8) ? src[h0*8 + n] : 0.f;
    float hi = (n<8) ? src[(h0+1)*8 + n] : 0.f;
    wsU[W2F1 + i] = pkh2(lo, hi);
    return;
  }
  i -= 7680;
  if (i < 1024){   // b1P0 natural [u][64]
    int u = i>>6;
    const float* src = (u<9) ? S.p[1]+u*64 : (u<12) ? S.p[5]+(u-9)*64
                     : (u<15) ? S.p[9]+(u-12)*64 : S.p[14];
    wsF[OFF_b1P0 + i] = src[i&63];
    return;
  }
  i -= 1024;
  if (i < 256){
    int u = i>>4, n = i&15;
    const float* src = (u<9) ? S.p[3]+u*8 : (u<12) ? S.p[7]+(u-9)*8
                     : (u<15) ? S.p[11]+(u-12)*8 : S.p[16];
    wsF[OFF_b2P0 + i] = (n<8) ? src[n] : 0.f;
    return;
  }
  i -= 256;
  if (i < 960){    // b1P1 natural [u][64]
    int u = i>>6;
    const float* src = (u<9) ? S.p[19]+u*64 : (u<12) ? S.p[23]+(u-9)*64
                               : S.p[27]+(u-12)*64;
    wsF[OFF_b1P1 + i] = src[i&63];
    return;
  }
  i -= 960;
  if (i < 240){
    int u = i>>4, n = i&15;
    const float* src = (u<9) ? S.p[21]+u*8 : (u<12) ? S.p[25]+(u-9)*8
                               : S.p[29]+(u-12)*8;
    wsF[OFF_b2P1 + i] = (n<8) ? src[n] : 0.f;
    return;
  }
  i -= 240;
  if (i < 144){ wsF[OFF_G0W3 + i] = S.p[12][i]; return; }
  i -= 144;
  if (i < 96){ wsF[OFF_SG0W3 + i] = S.p[17][i]; return; }
  i -= 96;
  if (i < 144){ wsF[OFF_G1W3 + i] = S.p[30][i]; return; }
  i -= 144;
  if (i < 24){ wsF[OFF_TW + i] = S.p[31][i]; return; }
  i -= 24;
  if (i < 3){ wsF[OFF_Tb + i] = S.p[32][i]; return; }
  i -= 3;
  { // TWH: [t][w] = pkh2(TW[t][2w], TW[t][2w+1])
    int t = i>>2, w = i&3;
    wsU[OFF_TWH + i] = pkh2(S.p[31][t*8 + 2*w], S.p[31][t*8 + 2*w + 1]);
  }
}

template<int N>
__device__ __forceinline__ void softmaxT(float (&v)[N]){
  float m = v[0];
  #pragma unroll
  for (int i=1;i<N;i++) m = fmaxf(m, v[i]);
  float s = 0.f;
  #pragma unroll
  for (int i=0;i<N;i++){ v[i] = __expf(v[i]-m); s += v[i]; }
  float inv = 1.f/s;
  #pragma unroll
  for (int i=0;i<N;i++) v[i] *= inv;
}

__global__ __launch_bounds__(NT, 4) void ple_kernel(
    const float* __restrict__ emb, const int* __restrict__ cat,
    const u32* __restrict__ wsU, const float* __restrict__ P,
    float* __restrict__ out, int Btot)
{
  // LDS (u32): xsA [64e][52] (x f16 pairs), aliased as l1in [64e][36].
  // obT [64e][68]: unit-major, u16 col = u*8 + n (u=0..15, n=0..7).
  __shared__ u32 S_[7680];
  u32* xsA = S_;            // 3328
  u32* obT = S_ + 3328;     // 4352
  const int tid = threadIdx.x;
  const int e = tid & 63;
  const int su = __builtin_amdgcn_readfirstlane(tid >> 6);
  const int lane = tid & 63;
  const int q = lane >> 4;
  const int c16 = lane & 15;

  // ---- phase 0: gather x -> xsA [e][52] f16 pairs, zero pad ----
  {
    const int eg = blockIdx.x*EPB + e;
    auto ldf = [&](int f){
      int idx = cat[eg*9 + f];
      const float* ep = emb + (long)idx*8;
      float4 a = *(const float4*)ep;
      float4 b = *(const float4*)(ep+4);
      uint4 w; w.x = pkh2(a.x,a.y); w.y = pkh2(a.z,a.w);
      w.z = pkh2(b.x,b.y); w.w = pkh2(b.z,b.w);
      *(uint4*)(xsA + e*52 + f*4) = w;
    };
    ldf(su); ldf(su+4);
    if (su == (e>>4)) ldf(8);   // spread field-8 across waves
    *(uint4*)(xsA + e*52 + 36 + su*4) = (uint4){0,0,0,0};
  }
  __syncthreads();

  // ---- phase 1: level-0, both GEMMs operand-swapped ----
  {
    #pragma unroll 1
    for (int k4 = 0; k4 < 4; k4++){
      const int u = su*4 + k4;
      half8 bf[3][4];
      #pragma unroll
      for (int s=0;s<3;s++)
        #pragma unroll
        for (int t=0;t<4;t++)
          bf[s][t] = *(const half8*)(wsU + W1F0 + (((u*3+s)*4+t)*64 + lane)*4);
      floatx4 bias[4];
      #pragma unroll
      for (int t=0;t<4;t++){
        float4 b4 = *(const float4*)(P + OFF_b1P0 + u*64 + t*16 + q*4);
        bias[t] = (floatx4){b4.x, b4.y, b4.z, b4.w};
      }
      float4 b2v = *(const float4*)(P + OFF_b2P0 + u*16 + q*4);
      half8 w2f[2];
      #pragma unroll
      for (int ks=0;ks<2;ks++)
        w2f[ks] = *(const half8*)(wsU + W2F0 + ((u*2+ks)*64 + lane)*4);

      #pragma unroll 4
      for (int m=0;m<4;m++){
        half8 af[3];
        #pragma unroll
        for (int s=0;s<3;s++)
          af[s] = *(const half8*)(xsA + (m*16 + c16)*52 + s*16 + q*4);
        floatx4 acc[4];
        #pragma unroll
        for (int t=0;t<4;t++) acc[t] = bias[t];
        #pragma unroll
        for (int s=0;s<3;s++)
          #pragma unroll
          for (int t=0;t<4;t++)
            acc[t] = __builtin_amdgcn_mfma_f32_16x16x32_f16(bf[s][t], af[s], acc[t], 0,0,0);
        // lane holds H[e=c16][h=t*16+q*4+r]; pack + f16-relu to W2-B frags
        floatx4 oc = (floatx4){b2v.x, b2v.y, b2v.z, b2v.w};
        #pragma unroll
        for (int ks=0;ks<2;ks++){
          u32 aw[4];
          aw[0] = pkrelu(acc[2*ks  ][0], acc[2*ks  ][1]);
          aw[1] = pkrelu(acc[2*ks  ][2], acc[2*ks  ][3]);
          aw[2] = pkrelu(acc[2*ks+1][0], acc[2*ks+1][1]);
          aw[3] = pkrelu(acc[2*ks+1][2], acc[2*ks+1][3]);
          half8 haf; __builtin_memcpy(&haf, aw, 16);
          oc = __builtin_amdgcn_mfma_f32_16x16x32_f16(w2f[ks], haf, oc, 0,0,0);
        }
        // lane holds O[e=c16][n=q*4+r]; q<2 covers n=0..7 -> one b64 store
        if (q < 2){
          uint2 ov;
          ov.x = pkrelu(oc[0], oc[1]);
          ov.y = pkrelu(oc[2], oc[3]);
          *(uint2*)(obT + (m*16 + c16)*68 + u*4 + q*2) = ov;
        }
      }
    }
  }
  __syncthreads();

  // ---- phase 2: level-0 gates + pk_fma mixing -> l1in [64e][36] ----
  u32* l1in = xsA;
  *(uint4*)(l1in + e*36 + 16 + su*4) = (uint4){0,0,0,0};
  {
    float wv[12];
    {
      const int ug = (su<3) ? 12+su : 15;
      uint4 gw = *(const uint4*)(obT + e*68 + ug*4);
      float g8[8]; unp8(gw, g8);
      if (su < 3){
        float lg[6];
        #pragma unroll
        for (int m=0;m<6;m++){
          float s = 0.f;
          #pragma unroll
          for (int j=0;j<8;j++) s = fmaf(g8[j], P[OFF_G0W3 + su*48 + j*6 + m], s);
          lg[m] = s;
        }
        softmaxT<6>(lg);
        #pragma unroll
        for (int k=0;k<12;k++)
          wv[k] = (k<9) ? (((k/3)==su) ? lg[k%3] : 0.f) : lg[k-6];
      } else {
        float lw[12];
        #pragma unroll
        for (int m=0;m<12;m++){
          float s = 0.f;
          #pragma unroll
          for (int j=0;j<8;j++) s = fmaf(g8[j], P[OFF_SG0W3 + j*12 + m], s);
          lw[m] = s;
        }
        softmaxT<12>(lw);
        #pragma unroll
        for (int k=0;k<12;k++) wv[k] = lw[k];
      }
    }
    hv2 a01 = (hv2){0,0}, a23 = (hv2){0,0}, a45 = (hv2){0,0}, a67 = (hv2){0,0};
    #pragma unroll
    for (int u=0;u<12;u++){
      uint4 ow = *(const uint4*)(obT + e*68 + u*4);
      __fp16 wh = (__fp16)wv[u];
      hv2 wp = (hv2){wh, wh};
      a01 = u2h(ow.x)*wp + a01;
      a23 = u2h(ow.y)*wp + a23;
      a45 = u2h(ow.z)*wp + a45;
      a67 = u2h(ow.w)*wp + a67;
    }
    const int dst = (su<3) ? su*4 : 12;
    uint4 lw4; lw4.x = h2u(a01); lw4.y = h2u(a23);
    lw4.z = h2u(a45); lw4.w = h2u(a67);
    *(uint4*)(l1in + e*36 + dst) = lw4;
  }
  __syncthreads();

  // ---- phase 3: level-1, operand-swapped GEMMs ----
  {
    #pragma unroll 1
    for (int k4=0;k4<4;k4++){
      const int u = su*4 + k4;
      if (u >= 15) break;
      const int base_u = (u<9) ? (u/3)*4 : ((u<12) ? 12 : (u-12)*4);
      const int aoff = (q==0) ? base_u : (16 + q*4);   // q>=1 -> zeros
      half8 bf1[4];
      #pragma unroll
      for (int t=0;t<4;t++)
        bf1[t] = *(const half8*)(wsU + W1F1 + ((u*4+t)*64 + lane)*4);
      floatx4 bias[4];
      #pragma unroll
      for (int t=0;t<4;t++){
        float4 b4 = *(const float4*)(P + OFF_b1P1 + u*64 + t*16 + q*4);
        bias[t] = (floatx4){b4.x, b4.y, b4.z, b4.w};
      }
      float4 b2v = *(const float4*)(P + OFF_b2P1 + u*16 + q*4);
      half8 w2f[2];
      #pragma unroll
      for (int ks=0;ks<2;ks++)
        w2f[ks] = *(const half8*)(wsU + W2F1 + ((u*2+ks)*64 + lane)*4);

      #pragma unroll 4
      for (int m=0;m<4;m++){
        half8 af = *(const half8*)(l1in + (m*16 + c16)*36 + aoff);
        floatx4 acc[4];
        #pragma unroll
        for (int t=0;t<4;t++) acc[t] = bias[t];
        #pragma unroll
        for (int t=0;t<4;t++)
          acc[t] = __builtin_amdgcn_mfma_f32_16x16x32_f16(bf1[t], af, acc[t], 0,0,0);
        floatx4 oc = (floatx4){b2v.x, b2v.y, b2v.z, b2v.w};
        #pragma unroll
        for (int ks=0;ks<2;ks++){
          u32 aw[4];
          aw[0] = pkrelu(acc[2*ks  ][0], acc[2*ks  ][1]);
          aw[1] = pkrelu(acc[2*ks  ][2], acc[2*ks  ][3]);
          aw[2] = pkrelu(acc[2*ks+1][0], acc[2*ks+1][1]);
          aw[3] = pkrelu(acc[2*ks+1][2], acc[2*ks+1][3]);
          half8 haf; __builtin_memcpy(&haf, aw, 16);
          oc = __builtin_amdgcn_mfma_f32_16x16x32_f16(w2f[ks], haf, oc, 0,0,0);
        }
        if (q < 2){
          uint2 ov;
          ov.x = pkrelu(oc[0], oc[1]);
          ov.y = pkrelu(oc[2], oc[3]);
          *(uint2*)(obT + (m*16 + c16)*68 + u*4 + q*2) = ov;
        }
      }
    }
  }
  __syncthreads();

  // ---- phase 4: level-1 gates + pk_fma mixing + towers ----
  if (su < 3){
    const int t = su;
    uint4 gw = *(const uint4*)(obT + e*68 + (12+t)*4);
    float g8[8]; unp8(gw, g8);
    float lg[6];
    #pragma unroll
    for (int m=0;m<6;m++){
      float s = 0.f;
      #pragma unroll
      for (int j=0;j<8;j++) s = fmaf(g8[j], P[OFF_G1W3 + t*48 + j*6 + m], s);
      lg[m] = s;
    }
    softmaxT<6>(lg);
    float wv[12];
    #pragma unroll
    for (int k=0;k<12;k++)
      wv[k] = (k<9) ? (((k/3)==t) ? lg[k%3] : 0.f) : lg[k-6];
    hv2 a01 = (hv2){0,0}, a23 = (hv2){0,0}, a45 = (hv2){0,0}, a67 = (hv2){0,0};
    #pragma unroll
    for (int u=0;u<12;u++){
      uint4 ow = *(const uint4*)(obT + e*68 + u*4);
      __fp16 wh = (__fp16)wv[u];
      hv2 wp = (hv2){wh, wh};
      a01 = u2h(ow.x)*wp + a01;
      a23 = u2h(ow.y)*wp + a23;
      a45 = u2h(ow.z)*wp + a45;
      a67 = u2h(ow.w)*wp + a67;
    }
    float s = P[OFF_Tb + t];
    s = dot2(h2u(a01), wsU[OFF_TWH + t*4 + 0], s);
    s = dot2(h2u(a23), wsU[OFF_TWH + t*4 + 1], s);
    s = dot2(h2u(a45), wsU[OFF_TWH + t*4 + 2], s);
    s = dot2(h2u(a67), wsU[OFF_TWH + t*4 + 3], s);
    out[t*Btot + blockIdx.x*EPB + e] = 1.f/(1.f + __expf(-s));
  }
}

extern "C" void kernel_launch(void* const* d_in, const int* in_sizes, int n_in,
                              void* d_out, int out_size, void* d_ws, size_t ws_size,
                              hipStream_t stream)
{
  const float* emb = (const float*)d_in[0];
  const int* cat = (const int*)d_in[34];
  float* out = (float*)d_out;
  u32* wsU = (u32*)d_ws;
  float* wsF = (float*)d_ws;
  PSrc S;
  for (int k=0;k<33;k++) S.p[k] = (const float*)d_in[k+1];
  const int B = in_sizes[34] / 9;   // 131072

  cvt_kernel<<<(CVT_TOTAL+255)/256, 256, 0, stream>>>(S, wsU, wsF);
  ple_kernel<<<B/EPB, NT, 0, stream>>>(emb, cat, wsU, wsF, out, B);
}

// Round 17
// 174.407 us; speedup vs baseline: 1.0705x; 1.0121x over previous
//
#include <hip/hip_runtime.h>

// PLELayer round-17: r16 with ILP across UNITS instead of across m.
// r16 post-mortem: m-unroll 4 was neutral (VGPR stayed 56; scheduler
// already saturated within a unit). The serially-exposed latency is the
// per-unit weight-frag global loads (14x b128 from L2, ~300cyc) at the
// top of each k4 iteration: pragma unroll 1 forbids cross-unit overlap.
// This round: #pragma unroll 2 on the k4 loops (phases 1+3) -> two
// units' frag loads + compute visible at once (register double-buffer).
// m-loops back to unroll 2. VGPR watch ~110 / cap 128; WRITE_SIZE is
// the spill tripwire.

#define NT 256
#define EPB 64

typedef unsigned short u16;
typedef unsigned int u32;
typedef __fp16 hv2 __attribute__((ext_vector_type(2)));
typedef __fp16 half8 __attribute__((ext_vector_type(8)));
typedef __attribute__((ext_vector_type(4))) float floatx4;

__device__ __forceinline__ u32 pkh2(float a, float b){
  hv2 v = __builtin_amdgcn_cvt_pkrtz(a, b);
  u32 r; __builtin_memcpy(&r, &v, 4); return r;
}
__device__ __forceinline__ float h2f(u16 v){
  __fp16 h; __builtin_memcpy(&h, &v, 2); return (float)h;
}
__device__ __forceinline__ hv2 u2h(u32 w){ hv2 v; __builtin_memcpy(&v, &w, 4); return v; }
__device__ __forceinline__ u32 h2u(hv2 v){ u32 w; __builtin_memcpy(&w, &v, 4); return w; }
__device__ __forceinline__ float dot2(u32 a, u32 b, float c){
  return __builtin_amdgcn_fdot2(u2h(a), u2h(b), c, false);
}
// pack two f32 then relu in f16 (v_cvt_pkrtz + v_pk_max_f16)
__device__ __forceinline__ u32 pkrelu(float a, float b){
  hv2 v = __builtin_amdgcn_cvt_pkrtz(a, b);
  hv2 z = (hv2){(__fp16)0.f, (__fp16)0.f};
  return h2u(__builtin_elementwise_max(v, z));
}
__device__ __forceinline__ void unp8(uint4 gw, float g8[8]){
  g8[0]=h2f((u16)(gw.x&0xffffu)); g8[1]=h2f((u16)(gw.x>>16));
  g8[2]=h2f((u16)(gw.y&0xffffu)); g8[3]=h2f((u16)(gw.y>>16));
  g8[4]=h2f((u16)(gw.z&0xffffu)); g8[5]=h2f((u16)(gw.z>>16));
  g8[6]=h2f((u16)(gw.w&0xffffu)); g8[7]=h2f((u16)(gw.w>>16));
}

// ---- ws layout ----
#define W1F0 0          // [16u][3s][4t][64l][4]  = 49152 u32 (f16 pairs)
#define W2F0 49152      // [16u][2ks][64l][4]     =  8192 (h'(q,ks,j) perm)
#define W1F1 57344      // [15u][4t][64l][4]      = 15360
#define W2F1 72704      // [15u][2ks][64l][4]     =  7680 (h' perm)
#define OFF_b1P0 80384  // [16][64] natural
#define OFF_b2P0 81408  // [16][16] cols 8..15 zero
#define OFF_b1P1 81664  // [15][64] natural
#define OFF_b2P1 82624  // [15][16] cols 8..15 zero
#define OFF_G0W3 82864  // [3][8][6]
#define OFF_SG0W3 83008 // [8][12]
#define OFF_G1W3 83104  // [3][8][6]
#define OFF_TW   83248  // [3][8] fp32 (unused by kernel now, kept)
#define OFF_Tb   83272  // [3]
#define OFF_TWH  83275  // [3][4] u32: packed f16 pairs of tower_W
#define CVT_TOTAL 83287

struct PSrc { const float* p[33]; };

__global__ void cvt_kernel(PSrc S, u32* __restrict__ wsU, float* __restrict__ wsF){
  int i = blockIdx.x*256 + threadIdx.x;
  if (i >= CVT_TOTAL) return;
  if (i < 49152){  // W1F0: lane holds W1[k=s*32+q*8+j][h=t*16+c16], k>=72 -> 0
    int j2 = i & 3, l = (i>>2)&63, tt = (i>>8)&3;
    int rest = i >> 10; int s = rest % 3, u = rest / 3;
    int k0 = s*32 + (l>>4)*8 + 2*j2;
    int h  = tt*16 + (l&15);
    const float* src = (u<9)  ? S.p[0]  + (u*72)*64
                     : (u<12) ? S.p[4]  + ((u-9)*72)*64
                     : (u<15) ? S.p[8]  + ((u-12)*72)*64
                              : S.p[13];
    float lo = (k0   < 72) ? src[(k0  )*64 + h] : 0.f;
    float hi = (k0+1 < 72) ? src[(k0+1)*64 + h] : 0.f;
    wsU[i] = pkh2(lo, hi);
    return;
  }
  i -= 49152;
  if (i < 8192){   // W2F0: W2[h'(q,ks,j)][n=l&15], n>=8 -> 0
    int j2 = i & 3, l = (i>>2)&63, ks = (i>>8)&1, u = i>>9;
    int q = l >> 4, n = l & 15;
    int h0 = (2*ks + ((2*j2)>>2))*16 + q*4 + ((2*j2)&3);
    const float* src = (u<9)  ? S.p[2]  + u*512
                     : (u<12) ? S.p[6]  + (u-9)*512
                     : (u<15) ? S.p[10] + (u-12)*512
                              : S.p[15];
    float lo = (n<8) ? src[h0*8 + n] : 0.f;
    float hi = (n<8) ? src[(h0+1)*8 + n] : 0.f;
    wsU[W2F0 + i] = pkh2(lo, hi);
    return;
  }
  i -= 8192;
  if (i < 15360){  // W1F1: lane holds W1[k=q*8+j][h=t*16+c16], k>=8 -> 0
    int j2 = i & 3, l = (i>>2)&63, tt = (i>>8)&3, u = i>>10;
    int k0 = (l>>4)*8 + 2*j2;
    int n = tt*16 + (l&15);
    const float* src = (u<9) ? S.p[18] + (u*8)*64
                     : (u<12) ? S.p[22] + ((u-9)*8)*64
                              : S.p[26] + ((u-12)*8)*64;
    float lo = (k0   < 8) ? src[(k0  )*64 + n] : 0.f;
    float hi = (k0+1 < 8) ? src[(k0+1)*64 + n] : 0.f;
    wsU[W1F1 + i] = pkh2(lo, hi);
    return;
  }
  i -= 15360;
  if (i < 7680){   // W2F1: h'(q,ks,j) permutation, n>=8 -> 0
    int j2 = i & 3, l = (i>>2)&63, ks = (i>>8)&1, u = i>>9;
    int q = l >> 4, n = l & 15;
    int h0 = (2*ks + ((2*j2)>>2))*16 + q*4 + ((2*j2)&3);
    const float* src = (u<9) ? S.p[20] + u*512
                     : (u<12) ? S.p[24] + (u-9)*512
                              : S.p[28] + (u-12)*512;
    float lo = (n<8) ? src[h0*8 + n] : 0.f;
    float hi = (n<8) ? src[(h0+1)*8 + n] : 0.f;
    wsU[W2F1 + i] = pkh2(lo, hi);
    return;
  }
  i -= 7680;
  if (i < 1024){   // b1P0 natural [u][64]
    int u = i>>6;
    const float* src = (u<9) ? S.p[1]+u*64 : (u<12) ? S.p[5]+(u-9)*64
                     : (u<15) ? S.p[9]+(u-12)*64 : S.p[14];
    wsF[OFF_b1P0 + i] = src[i&63];
    return;
  }
  i -= 1024;
  if (i < 256){
    int u = i>>4, n = i&15;
    const float* src = (u<9) ? S.p[3]+u*8 : (u<12) ? S.p[7]+(u-9)*8
                     : (u<15) ? S.p[11]+(u-12)*8 : S.p[16];
    wsF[OFF_b2P0 + i] = (n<8) ? src[n] : 0.f;
    return;
  }
  i -= 256;
  if (i < 960){    // b1P1 natural [u][64]
    int u = i>>6;
    const float* src = (u<9) ? S.p[19]+u*64 : (u<12) ? S.p[23]+(u-9)*64
                               : S.p[27]+(u-12)*64;
    wsF[OFF_b1P1 + i] = src[i&63];
    return;
  }
  i -= 960;
  if (i < 240){
    int u = i>>4, n = i&15;
    const float* src = (u<9) ? S.p[21]+u*8 : (u<12) ? S.p[25]+(u-9)*8
                               : S.p[29]+(u-12)*8;
    wsF[OFF_b2P1 + i] = (n<8) ? src[n] : 0.f;
    return;
  }
  i -= 240;
  if (i < 144){ wsF[OFF_G0W3 + i] = S.p[12][i]; return; }
  i -= 144;
  if (i < 96){ wsF[OFF_SG0W3 + i] = S.p[17][i]; return; }
  i -= 96;
  if (i < 144){ wsF[OFF_G1W3 + i] = S.p[30][i]; return; }
  i -= 144;
  if (i < 24){ wsF[OFF_TW + i] = S.p[31][i]; return; }
  i -= 24;
  if (i < 3){ wsF[OFF_Tb + i] = S.p[32][i]; return; }
  i -= 3;
  { // TWH: [t][w] = pkh2(TW[t][2w], TW[t][2w+1])
    int t = i>>2, w = i&3;
    wsU[OFF_TWH + i] = pkh2(S.p[31][t*8 + 2*w], S.p[31][t*8 + 2*w + 1]);
  }
}

template<int N>
__device__ __forceinline__ void softmaxT(float (&v)[N]){
  float m = v[0];
  #pragma unroll
  for (int i=1;i<N;i++) m = fmaxf(m, v[i]);
  float s = 0.f;
  #pragma unroll
  for (int i=0;i<N;i++){ v[i] = __expf(v[i]-m); s += v[i]; }
  float inv = 1.f/s;
  #pragma unroll
  for (int i=0;i<N;i++) v[i] *= inv;
}

__global__ __launch_bounds__(NT, 4) void ple_kernel(
    const float* __restrict__ emb, const int* __restrict__ cat,
    const u32* __restrict__ wsU, const float* __restrict__ P,
    float* __restrict__ out, int Btot)
{
  // LDS (u32): xsA [64e][52] (x f16 pairs), aliased as l1in [64e][36].
  // obT [64e][68]: unit-major, u16 col = u*8 + n (u=0..15, n=0..7).
  __shared__ u32 S_[7680];
  u32* xsA = S_;            // 3328
  u32* obT = S_ + 3328;     // 4352
  const int tid = threadIdx.x;
  const int e = tid & 63;
  const int su = __builtin_amdgcn_readfirstlane(tid >> 6);
  const int lane = tid & 63;
  const int q = lane >> 4;
  const int c16 = lane & 15;

  // ---- phase 0: gather x -> xsA [e][52] f16 pairs, zero pad ----
  {
    const int eg = blockIdx.x*EPB + e;
    auto ldf = [&](int f){
      int idx = cat[eg*9 + f];
      const float* ep = emb + (long)idx*8;
      float4 a = *(const float4*)ep;
      float4 b = *(const float4*)(ep+4);
      uint4 w; w.x = pkh2(a.x,a.y); w.y = pkh2(a.z,a.w);
      w.z = pkh2(b.x,b.y); w.w = pkh2(b.z,b.w);
      *(uint4*)(xsA + e*52 + f*4) = w;
    };
    ldf(su); ldf(su+4);
    if (su == (e>>4)) ldf(8);   // spread field-8 across waves
    *(uint4*)(xsA + e*52 + 36 + su*4) = (uint4){0,0,0,0};
  }
  __syncthreads();

  // ---- phase 1: level-0, both GEMMs operand-swapped ----
  {
    #pragma unroll 2
    for (int k4 = 0; k4 < 4; k4++){
      const int u = su*4 + k4;
      half8 bf[3][4];
      #pragma unroll
      for (int s=0;s<3;s++)
        #pragma unroll
        for (int t=0;t<4;t++)
          bf[s][t] = *(const half8*)(wsU + W1F0 + (((u*3+s)*4+t)*64 + lane)*4);
      floatx4 bias[4];
      #pragma unroll
      for (int t=0;t<4;t++){
        float4 b4 = *(const float4*)(P + OFF_b1P0 + u*64 + t*16 + q*4);
        bias[t] = (floatx4){b4.x, b4.y, b4.z, b4.w};
      }
      float4 b2v = *(const float4*)(P + OFF_b2P0 + u*16 + q*4);
      half8 w2f[2];
      #pragma unroll
      for (int ks=0;ks<2;ks++)
        w2f[ks] = *(const half8*)(wsU + W2F0 + ((u*2+ks)*64 + lane)*4);

      #pragma unroll 2
      for (int m=0;m<4;m++){
        half8 af[3];
        #pragma unroll
        for (int s=0;s<3;s++)
          af[s] = *(const half8*)(xsA + (m*16 + c16)*52 + s*16 + q*4);
        floatx4 acc[4];
        #pragma unroll
        for (int t=0;t<4;t++) acc[t] = bias[t];
        #pragma unroll
        for (int s=0;s<3;s++)
          #pragma unroll
          for (int t=0;t<4;t++)
            acc[t] = __builtin_amdgcn_mfma_f32_16x16x32_f16(bf[s][t], af[s], acc[t], 0,0,0);
        // lane holds H[e=c16][h=t*16+q*4+r]; pack + f16-relu to W2-B frags
        floatx4 oc = (floatx4){b2v.x, b2v.y, b2v.z, b2v.w};
        #pragma unroll
        for (int ks=0;ks<2;ks++){
          u32 aw[4];
          aw[0] = pkrelu(acc[2*ks  ][0], acc[2*ks  ][1]);
          aw[1] = pkrelu(acc[2*ks  ][2], acc[2*ks  ][3]);
          aw[2] = pkrelu(acc[2*ks+1][0], acc[2*ks+1][1]);
          aw[3] = pkrelu(acc[2*ks+1][2], acc[2*ks+1][3]);
          half8 haf; __builtin_memcpy(&haf, aw, 16);
          oc = __builtin_amdgcn_mfma_f32_16x16x32_f16(w2f[ks], haf, oc, 0,0,0);
        }
        // lane holds O[e=c16][n=q*4+r]; q<2 covers n=0..7 -> one b64 store
        if (q < 2){
          uint2 ov;
          ov.x = pkrelu(oc[0], oc[1]);
          ov.y = pkrelu(oc[2], oc[3]);
          *(uint2*)(obT + (m*16 + c16)*68 + u*4 + q*2) = ov;
        }
      }
    }
  }
  __syncthreads();

  // ---- phase 2: level-0 gates + pk_fma mixing -> l1in [64e][36] ----
  u32* l1in = xsA;
  *(uint4*)(l1in + e*36 + 16 + su*4) = (uint4){0,0,0,0};
  {
    float wv[12];
    {
      const int ug = (su<3) ? 12+su : 15;
      uint4 gw = *(const uint4*)(obT + e*68 + ug*4);
      float g8[8]; unp8(gw, g8);
      if (su < 3){
        float lg[6];
        #pragma unroll
        for (int m=0;m<6;m++){
          float s = 0.f;
          #pragma unroll
          for (int j=0;j<8;j++) s = fmaf(g8[j], P[OFF_G0W3 + su*48 + j*6 + m], s);
          lg[m] = s;
        }
        softmaxT<6>(lg);
        #pragma unroll
        for (int k=0;k<12;k++)
          wv[k] = (k<9) ? (((k/3)==su) ? lg[k%3] : 0.f) : lg[k-6];
      } else {
        float lw[12];
        #pragma unroll
        for (int m=0;m<12;m++){
          float s = 0.f;
          #pragma unroll
          for (int j=0;j<8;j++) s = fmaf(g8[j], P[OFF_SG0W3 + j*12 + m], s);
          lw[m] = s;
        }
        softmaxT<12>(lw);
        #pragma unroll
        for (int k=0;k<12;k++) wv[k] = lw[k];
      }
    }
    hv2 a01 = (hv2){0,0}, a23 = (hv2){0,0}, a45 = (hv2){0,0}, a67 = (hv2){0,0};
    #pragma unroll
    for (int u=0;u<12;u++){
      uint4 ow = *(const uint4*)(obT + e*68 + u*4);
      __fp16 wh = (__fp16)wv[u];
      hv2 wp = (hv2){wh, wh};
      a01 = u2h(ow.x)*wp + a01;
      a23 = u2h(ow.y)*wp + a23;
      a45 = u2h(ow.z)*wp + a45;
      a67 = u2h(ow.w)*wp + a67;
    }
    const int dst = (su<3) ? su*4 : 12;
    uint4 lw4; lw4.x = h2u(a01); lw4.y = h2u(a23);
    lw4.z = h2u(a45); lw4.w = h2u(a67);
    *(uint4*)(l1in + e*36 + dst) = lw4;
  }
  __syncthreads();

  // ---- phase 3: level-1, operand-swapped GEMMs ----
  {
    #pragma unroll 2
    for (int k4=0;k4<4;k4++){
      const int u = su*4 + k4;
      if (u >= 15) break;
      const int base_u = (u<9) ? (u/3)*4 : ((u<12) ? 12 : (u-12)*4);
      const int aoff = (q==0) ? base_u : (16 + q*4);   // q>=1 -> zeros
      half8 bf1[4];
      #pragma unroll
      for (int t=0;t<4;t++)
        bf1[t] = *(const half8*)(wsU + W1F1 + ((u*4+t)*64 + lane)*4);
      floatx4 bias[4];
      #pragma unroll
      for (int t=0;t<4;t++){
        float4 b4 = *(const float4*)(P + OFF_b1P1 + u*64 + t*16 + q*4);
        bias[t] = (floatx4){b4.x, b4.y, b4.z, b4.w};
      }
      float4 b2v = *(const float4*)(P + OFF_b2P1 + u*16 + q*4);
      half8 w2f[2];
      #pragma unroll
      for (int ks=0;ks<2;ks++)
        w2f[ks] = *(const half8*)(wsU + W2F1 + ((u*2+ks)*64 + lane)*4);

      #pragma unroll 2
      for (int m=0;m<4;m++){
        half8 af = *(const half8*)(l1in + (m*16 + c16)*36 + aoff);
        floatx4 acc[4];
        #pragma unroll
        for (int t=0;t<4;t++) acc[t] = bias[t];
        #pragma unroll
        for (int t=0;t<4;t++)
          acc[t] = __builtin_amdgcn_mfma_f32_16x16x32_f16(bf1[t], af, acc[t], 0,0,0);
        floatx4 oc = (floatx4){b2v.x, b2v.y, b2v.z, b2v.w};
        #pragma unroll
        for (int ks=0;ks<2;ks++){
          u32 aw[4];
          aw[0] = pkrelu(acc[2*ks  ][0], acc[2*ks  ][1]);
          aw[1] = pkrelu(acc[2*ks  ][2], acc[2*ks  ][3]);
          aw[2] = pkrelu(acc[2*ks+1][0], acc[2*ks+1][1]);
          aw[3] = pkrelu(acc[2*ks+1][2], acc[2*ks+1][3]);
          half8 haf; __builtin_memcpy(&haf, aw, 16);
          oc = __builtin_amdgcn_mfma_f32_16x16x32_f16(w2f[ks], haf, oc, 0,0,0);
        }
        if (q < 2){
          uint2 ov;
          ov.x = pkrelu(oc[0], oc[1]);
          ov.y = pkrelu(oc[2], oc[3]);
          *(uint2*)(obT + (m*16 + c16)*68 + u*4 + q*2) = ov;
        }
      }
    }
  }
  __syncthreads();

  // ---- phase 4: level-1 gates + pk_fma mixing + towers ----
  if (su < 3){
    const int t = su;
    uint4 gw = *(const uint4*)(obT + e*68 + (12+t)*4);
    float g8[8]; unp8(gw, g8);
    float lg[6];
    #pragma unroll
    for (int m=0;m<6;m++){
      float s = 0.f;
      #pragma unroll
      for (int j=0;j<8;j++) s = fmaf(g8[j], P[OFF_G1W3 + t*48 + j*6 + m], s);
      lg[m] = s;
    }
    softmaxT<6>(lg);
    float wv[12];
    #pragma unroll
    for (int k=0;k<12;k++)
      wv[k] = (k<9) ? (((k/3)==t) ? lg[k%3] : 0.f) : lg[k-6];
    hv2 a01 = (hv2){0,0}, a23 = (hv2){0,0}, a45 = (hv2){0,0}, a67 = (hv2){0,0};
    #pragma unroll
    for (int u=0;u<12;u++){
      uint4 ow = *(const uint4*)(obT + e*68 + u*4);
      __fp16 wh = (__fp16)wv[u];
      hv2 wp = (hv2){wh, wh};
      a01 = u2h(ow.x)*wp + a01;
      a23 = u2h(ow.y)*wp + a23;
      a45 = u2h(ow.z)*wp + a45;
      a67 = u2h(ow.w)*wp + a67;
    }
    float s = P[OFF_Tb + t];
    s = dot2(h2u(a01), wsU[OFF_TWH + t*4 + 0], s);
    s = dot2(h2u(a23), wsU[OFF_TWH + t*4 + 1], s);
    s = dot2(h2u(a45), wsU[OFF_TWH + t*4 + 2], s);
    s = dot2(h2u(a67), wsU[OFF_TWH + t*4 + 3], s);
    out[t*Btot + blockIdx.x*EPB + e] = 1.f/(1.f + __expf(-s));
  }
}

extern "C" void kernel_launch(void* const* d_in, const int* in_sizes, int n_in,
                              void* d_out, int out_size, void* d_ws, size_t ws_size,
                              hipStream_t stream)
{
  const float* emb = (const float*)d_in[0];
  const int* cat = (const int*)d_in[34];
  float* out = (float*)d_out;
  u32* wsU = (u32*)d_ws;
  float* wsF = (float*)d_ws;
  PSrc S;
  for (int k=0;k<33;k++) S.p[k] = (const float*)d_in[k+1];
  const int B = in_sizes[34] / 9;   // 131072

  cvt_kernel<<<(CVT_TOTAL+255)/256, 256, 0, stream>>>(S, wsU, wsF);
  ple_kernel<<<B/EPB, NT, 0, stream>>>(emb, cat, wsU, wsF, out, B);
}